// Round 2
// baseline (502.464 us; speedup 1.0000x reference)
//
#include <hip/hip_runtime.h>
#include <hip/hip_bf16.h>
#include <stdint.h>

// LcRnnCell DEPTH=1, B=4096, E=H=512. Split-bf16 MFMA implementation.
// pd==0 rows: na10=[X,b_dm1]@Wa10^T ; nb10=[X,na10]@Wb10^T ; sel forced col2.
// pd==1 rows: nb11=[X,b_d]@Wb11^T ; na00=[X,b_dm1,a_d]@Wa00^T (hoisted for all);
//             z from [0,a_d,b_d,0,a_d,nb11]; sel over {0,1,3};
//             sel0: nb00=[X,a_d,na00]@Wb00^T ; sel3: copy [a_d; nb11]; ties additive.
// All matmuls: 3-product split-bf16 (hi*hi + hi*lo + lo*hi), fp32 accumulate.
// Packed operand layout: [row][kb][slot0..7] where slot s<4 = hi bf16 of k=8s..8s+7
// (within the 32-wide kb), slot s>=4 = lo of k=8(s-4).. ; 128B per (row,kb).

typedef __attribute__((ext_vector_type(8))) short bf16x8;
typedef __attribute__((ext_vector_type(4))) float f32x4;

#define MB_ ((size_t)1 << 20)

static __device__ __forceinline__ unsigned short f2bf(float x) {
  unsigned int u = __float_as_uint(x);
  unsigned int r = (u + 0x7FFFu + ((u >> 16) & 1u)) >> 16;
  return (unsigned short)r;
}
static __device__ __forceinline__ float bf2f(unsigned short b) {
  return __uint_as_float(((unsigned int)b) << 16);
}
// reconstruct fp32 value (hi+lo) from packed array at row-base `base`, k index k
static __device__ __forceinline__ float unpk(const unsigned short* p, long base, int k) {
  long a = base + ((long)(k >> 5) << 6) + (long)(((k >> 3) & 3) << 3) + (k & 7);
  return bf2f(p[a]) + bf2f(p[a + 32]);
}

__global__ void kz(float4* out, int* cnt, long n4) {
  long i = (long)blockIdx.x * blockDim.x + threadIdx.x;
  long st = (long)gridDim.x * blockDim.x;
  float4 z = make_float4(0.f, 0.f, 0.f, 0.f);
  for (; i < n4; i += st) out[i] = z;
  if (blockIdx.x == 0 && threadIdx.x < 16) cnt[threadIdx.x] = 0;
}

struct CvtSeg { const float* src; unsigned short* dst; int srcStride; int gprow; long gbase; };
struct CvtArgs { CvtSeg s[9]; long total; };

__global__ void kcvt(CvtArgs a) {
  long g0 = (long)blockIdx.x * blockDim.x + threadIdx.x;
  long st = (long)gridDim.x * blockDim.x;
  for (long g = g0; g < a.total; g += st) {
    const float* src = a.s[0].src;
    unsigned short* dst = a.s[0].dst;
    int stride = a.s[0].srcStride, gp = a.s[0].gprow;
    long base = 0;
#pragma unroll
    for (int t = 1; t < 9; ++t) {
      if (g >= a.s[t].gbase) {
        src = a.s[t].src; dst = a.s[t].dst;
        stride = a.s[t].srcStride; gp = a.s[t].gprow; base = a.s[t].gbase;
      }
    }
    long lg = g - base;
    int row = (int)(lg / gp);
    int kp = (int)(lg - (long)row * gp);
    const float* p = src + (long)row * stride + kp * 8;
    float4 v0 = *(const float4*)p;
    float4 v1 = *(const float4*)(p + 4);
    float v[8] = {v0.x, v0.y, v0.z, v0.w, v1.x, v1.y, v1.z, v1.w};
    unsigned int hw[4], lw[4];
#pragma unroll
    for (int j = 0; j < 4; ++j) {
      unsigned short h0 = f2bf(v[2 * j]), h1 = f2bf(v[2 * j + 1]);
      unsigned short l0 = f2bf(v[2 * j] - bf2f(h0));
      unsigned short l1 = f2bf(v[2 * j + 1] - bf2f(h1));
      hw[j] = (unsigned)h0 | ((unsigned)h1 << 16);
      lw[j] = (unsigned)l0 | ((unsigned)l1 << 16);
    }
    unsigned short* d = dst + (long)row * ((long)gp * 16) + (long)(kp >> 2) * 64 + (kp & 3) * 8;
    *(uint4*)d = make_uint4(hw[0], hw[1], hw[2], hw[3]);
    *(uint4*)(d + 32) = make_uint4(lw[0], lw[1], lw[2], lw[3]);
  }
}

__global__ void kclassify(const int* __restrict__ pdep, float* dep, float* fo, float* jo,
                          int* cnt, int* list0, int* list1, int Bn) {
  int r = blockIdx.x * blockDim.x + threadIdx.x;
  if (r >= Bn) return;
  if (pdep[r] == 0) {
    int p = atomicAdd(&cnt[0], 1);
    list0[p] = r;
    dep[r] = 1.0f; fo[r] = 1.0f; jo[r] = 0.0f;
  } else {
    int p = atomicAdd(&cnt[1], 1);
    list1[p] = r;
  }
}

struct GArgs {
  unsigned short *Xp, *pb0p, *pb1p, *pa1p, *na10p, *na00p, *nb11p;
  const unsigned short *Wa10p, *Wb10p, *Wb11p, *Wa00p, *Wb00p;
  float *nextA, *nextB;
  const int *cnt, *list0, *list1, *list2, *list2i;
};

// modes: 0=A10, 1=B11, 2=A00, 3=B10, 4=B00
template <int BM, bool FUSED>
__global__ __launch_bounds__(256) void gemm_mfma(GArgs G, int modeArg) {
  const int NA = BM / 32;   // A stage units per thread
  const int NRB = BM / 32;  // 16-row fragment tiles per wave (wave rows = BM/2)
  int nt = (int)(blockIdx.x & 7);
  int mtg = (int)(blockIdx.x >> 3);
  int mode, mt;
  if (FUSED) { mode = mtg >> 5; mt = mtg & 31; }
  else { mode = modeArg; mt = mtg; }

  const int* lst; int cntv; int ksteps; const unsigned short* W; int wstride;
  const unsigned short *sb0 = G.Xp, *sb1 = nullptr, *sb2 = nullptr;
  const int *si0 = nullptr, *si1 = nullptr, *si2 = nullptr;
  if (mode == 0) {
    lst = G.list0; cntv = G.cnt[0]; ksteps = 32; W = G.Wa10p; wstride = 2048;
    sb1 = G.pb0p; si0 = si1 = G.list0;
  } else if (mode == 1) {
    lst = G.list1; cntv = G.cnt[1]; ksteps = 32; W = G.Wb11p; wstride = 2048;
    sb1 = G.pb1p; si0 = si1 = G.list1;
  } else if (mode == 2) {
    lst = G.list1; cntv = G.cnt[1]; ksteps = 48; W = G.Wa00p; wstride = 3072;
    sb1 = G.pb0p; sb2 = G.pa1p; si0 = si1 = si2 = G.list1;
  } else if (mode == 3) {
    lst = G.list0; cntv = G.cnt[0]; ksteps = 32; W = G.Wb10p; wstride = 2048;
    sb1 = G.na10p; si0 = G.list0; si1 = nullptr;  // na10p linear by list0-position
  } else {
    lst = G.list2; cntv = G.cnt[2]; ksteps = 48; W = G.Wb00p; wstride = 3072;
    sb1 = G.pa1p; sb2 = G.na00p; si0 = si1 = G.list2; si2 = G.list2i;
  }
  if (mt * BM >= cntv) return;

  const int tid = threadIdx.x;
  // per-unit gathered row indices (constant over K)
  int ridx0[NA], ridx1[NA], ridx2[NA];
#pragma unroll
  for (int u = 0; u < NA; ++u) {
    int unit = tid * NA + u;
    int row = unit >> 3;
    int mg = mt * BM + row;
    if (mg > cntv - 1) mg = cntv - 1;
    ridx0[u] = si0 ? si0[mg] : mg;
    ridx1[u] = si1 ? si1[mg] : mg;
    ridx2[u] = si2 ? si2[mg] : mg;
  }
  long wb[2];
#pragma unroll
  for (int u = 0; u < 2; ++u) {
    int unit = tid * 2 + u;
    int col = unit >> 3, s = unit & 7;
    wb[u] = (long)(nt * 64 + col) * wstride + s * 8;
  }

  __shared__ unsigned short lds[(8 * BM + 8 * 64) * 8];
  const int ABASE = 8 * BM * 8;

  uint4 ap[NA], bp[2];
  auto loadAB = [&](int kb) {
    int seg = kb >> 4, kl = kb & 15;
    const unsigned short* sb = (seg == 0) ? sb0 : ((seg == 1) ? sb1 : sb2);
#pragma unroll
    for (int u = 0; u < NA; ++u) {
      int rix = (seg == 0) ? ridx0[u] : ((seg == 1) ? ridx1[u] : ridx2[u]);
      int unit = tid * NA + u;
      int s = unit & 7;
      ap[u] = *(const uint4*)(sb + (long)rix * 1024 + kl * 64 + s * 8);
    }
#pragma unroll
    for (int u = 0; u < 2; ++u) bp[u] = *(const uint4*)(W + wb[u] + (long)kb * 64);
  };
  auto storeLDS = [&]() {
#pragma unroll
    for (int u = 0; u < NA; ++u) {
      int unit = tid * NA + u;
      int row = unit >> 3, s = unit & 7;
      *(uint4*)&lds[(s * BM + row) * 8] = ap[u];
    }
#pragma unroll
    for (int u = 0; u < 2; ++u) {
      int unit = tid * 2 + u;
      int col = unit >> 3, s = unit & 7;
      *(uint4*)&lds[ABASE + (s * 64 + col) * 8] = bp[u];
    }
  };

  const int w = tid >> 6, lane = tid & 63;
  const int wrow = (w >> 1) * (BM / 2), wcol = (w & 1) * 32;
  const int g = lane >> 4, lr = lane & 15;

  f32x4 acc[NRB][2];
#pragma unroll
  for (int i = 0; i < NRB; ++i)
#pragma unroll
    for (int j = 0; j < 2; ++j) acc[i][j] = (f32x4){0.f, 0.f, 0.f, 0.f};

  loadAB(0);
  storeLDS();
  __syncthreads();
  for (int kb = 0; kb < ksteps; ++kb) {
    if (kb + 1 < ksteps) loadAB(kb + 1);
    bf16x8 ah[NRB], al[NRB], bh[2], bl[2];
#pragma unroll
    for (int rb = 0; rb < NRB; ++rb) {
      int r = wrow + rb * 16 + lr;
      ah[rb] = *(const bf16x8*)&lds[(g * BM + r) * 8];
      al[rb] = *(const bf16x8*)&lds[((g + 4) * BM + r) * 8];
    }
#pragma unroll
    for (int cb = 0; cb < 2; ++cb) {
      int c = wcol + cb * 16 + lr;
      bh[cb] = *(const bf16x8*)&lds[ABASE + (g * 64 + c) * 8];
      bl[cb] = *(const bf16x8*)&lds[ABASE + ((g + 4) * 64 + c) * 8];
    }
#pragma unroll
    for (int rb = 0; rb < NRB; ++rb)
#pragma unroll
      for (int cb = 0; cb < 2; ++cb) {
        acc[rb][cb] = __builtin_amdgcn_mfma_f32_16x16x32_bf16(ah[rb], bh[cb], acc[rb][cb], 0, 0, 0);
        acc[rb][cb] = __builtin_amdgcn_mfma_f32_16x16x32_bf16(ah[rb], bl[cb], acc[rb][cb], 0, 0, 0);
        acc[rb][cb] = __builtin_amdgcn_mfma_f32_16x16x32_bf16(al[rb], bh[cb], acc[rb][cb], 0, 0, 0);
      }
    __syncthreads();
    if (kb + 1 < ksteps) { storeLDS(); __syncthreads(); }
  }

  // epilogue: C row = wrow+rb*16+(lane>>4)*4+e, col = nt*64+wcol+cb*16+(lane&15)
#pragma unroll
  for (int rb = 0; rb < NRB; ++rb) {
#pragma unroll
    for (int e = 0; e < 4; ++e) {
      int m = wrow + rb * 16 + (lane >> 4) * 4 + e;
      int mg = mt * BM + m;
      if (mg >= cntv) continue;
      long r = 0;
      if (mode == 0 || mode == 3 || mode == 4) r = lst[mg];
#pragma unroll
      for (int cb = 0; cb < 2; ++cb) {
        int n = nt * 64 + wcol + cb * 16 + lr;
        float v = acc[rb][cb][e];
        long a = (long)mg * 1024 + (long)((n >> 5) << 6) + (long)(((n >> 3) & 3) << 3) + (n & 7);
        if (mode == 0) {
          G.nextA[r * 1024 + 512 + n] = v;
          unsigned short h = f2bf(v);
          G.na10p[a] = h; G.na10p[a + 32] = f2bf(v - bf2f(h));
        } else if (mode == 1) {
          unsigned short h = f2bf(v);
          G.nb11p[a] = h; G.nb11p[a + 32] = f2bf(v - bf2f(h));
        } else if (mode == 2) {
          unsigned short h = f2bf(v);
          G.na00p[a] = h; G.na00p[a + 32] = f2bf(v - bf2f(h));
        } else if (mode == 3) {
          G.nextB[r * 1024 + 512 + n] = v;
        } else {
          G.nextB[r * 1024 + 512 + n] += v;  // adds onto kselect's s3*nb11 (tie-safe)
        }
      }
    }
  }
}

__global__ __launch_bounds__(64) void kselect(
    const float* __restrict__ pa, const float* __restrict__ pb,
    const float* __restrict__ watt,
    const unsigned short* __restrict__ nb11p, const unsigned short* __restrict__ na00p,
    float* nextA, float* nextB, float* dep, float* fo, float* jo,
    int* cnt, const int* __restrict__ list1, int* list2, int* list2i) {
  int i1 = blockIdx.x;
  if (i1 >= cnt[1]) return;
  int r = list1[i1];
  int lane = threadIdx.x;
  const float* a_d = pa + (long)r * 1024 + 512;
  const float* b_d = pb + (long)r * 1024 + 512;
  long nbb = (long)i1 * 1024;
  float av[8], nv[8];
  float z0 = 0.f, z1 = 0.f, z2 = 0.f, z3 = 0.f;
#pragma unroll
  for (int u = 0; u < 8; ++u) {
    int h = u * 64 + lane;
    float la = a_d[h], lb = b_d[h], ln = unpk(nb11p, nbb, h);
    av[u] = la; nv[u] = ln;
    // z input = [0(1024), a_d, b_d, 0(1024), a_d, nb11]
    z0 += (watt[0 * 4096 + 1024 + h] + watt[0 * 4096 + 3072 + h]) * la +
          watt[0 * 4096 + 1536 + h] * lb + watt[0 * 4096 + 3584 + h] * ln;
    z1 += (watt[1 * 4096 + 1024 + h] + watt[1 * 4096 + 3072 + h]) * la +
          watt[1 * 4096 + 1536 + h] * lb + watt[1 * 4096 + 3584 + h] * ln;
    z2 += (watt[2 * 4096 + 1024 + h] + watt[2 * 4096 + 3072 + h]) * la +
          watt[2 * 4096 + 1536 + h] * lb + watt[2 * 4096 + 3584 + h] * ln;
    z3 += (watt[3 * 4096 + 1024 + h] + watt[3 * 4096 + 3072 + h]) * la +
          watt[3 * 4096 + 1536 + h] * lb + watt[3 * 4096 + 3584 + h] * ln;
  }
#pragma unroll
  for (int off = 32; off; off >>= 1) {
    z0 += __shfl_xor(z0, off); z1 += __shfl_xor(z1, off);
    z2 += __shfl_xor(z2, off); z3 += __shfl_xor(z3, off);
  }
  float m = fmaxf(fmaxf(z0, z1), fmaxf(z2, z3));
  float e0 = expf(z0 - m), e1 = expf(z1 - m), e2 = expf(z2 - m), e3 = expf(z3 - m);
  float s = e0 + e1 + e2 + e3;
  float att0 = e0 / s, att1 = e1 / s, att3 = e3 / s;  // att2 masked (pd==1)
  float amax = fmaxf(att0, fmaxf(att1, att3));
  float s0 = (att0 >= amax) ? 1.f : 0.f;
  float s1v = (att1 >= amax) ? 1.f : 0.f;
  float s3 = (att3 >= amax) ? 1.f : 0.f;
  if (lane == 0) {
    dep[r] = s0 + s3;   // sel0*1 + sel1*0 + sel3*1
    fo[r] = s3;         // sel2+sel3
    jo[r] = s1v + s3;   // sel1+sel3
    if (s0 > 0.f) { int p = atomicAdd(&cnt[2], 1); list2[p] = r; list2i[p] = i1; }
  }
  if (s0 + s3 > 0.f) {
    float* dA = nextA + (long)r * 1024 + 512;
    float* dB = nextB + (long)r * 1024 + 512;
#pragma unroll
    for (int u = 0; u < 8; ++u) {
      int h = u * 64 + lane;
      float va = s3 * av[u];
      if (s0 > 0.f) va += unpk(na00p, nbb, h);
      dA[h] = va;
      dB[h] = s3 * nv[u];  // B00 adds nb00 later for sel0 rows
    }
  }
}

extern "C" void kernel_launch(void* const* d_in, const int* in_sizes, int n_in,
                              void* d_out, int out_size, void* d_ws, size_t ws_size,
                              hipStream_t stream) {
  const float* X = (const float*)d_in[0];
  const float* pa = (const float*)d_in[1];
  const float* pb = (const float*)d_in[2];
  const int* pdep = (const int*)d_in[3];
  const float* Wa00 = (const float*)d_in[4];
  const float* Wa10 = (const float*)d_in[5];
  const float* Wb00 = (const float*)d_in[6];
  const float* Wb11 = (const float*)d_in[7];
  const float* Wb10 = (const float*)d_in[8];
  const float* Watt = (const float*)d_in[10];  // d_in[9]=Wb01 unused (nb01==0)
  const int Bn = in_sizes[3];

  float* out = (float*)d_out;
  float* nextA = out;
  float* nextB = out + (long)Bn * 1024;
  float* dep = out + (long)2 * Bn * 1024;
  float* fo = dep + Bn;
  float* jo = fo + Bn;

  char* ws = (char*)d_ws;
  int* cnt = (int*)ws;
  int* list0 = (int*)(ws + 1024);
  int* list1 = (int*)(ws + 1024 + 16384);
  int* list2 = (int*)(ws + 1024 + 2 * 16384);
  int* list2i = (int*)(ws + 1024 + 3 * 16384);
  unsigned short* Xp    = (unsigned short*)(ws + 1 * MB_);
  unsigned short* pb0p  = (unsigned short*)(ws + 9 * MB_);
  unsigned short* pb1p  = (unsigned short*)(ws + 17 * MB_);
  unsigned short* pa1p  = (unsigned short*)(ws + 25 * MB_);
  unsigned short* na10p = (unsigned short*)(ws + 33 * MB_);
  unsigned short* na00p = (unsigned short*)(ws + 41 * MB_);
  unsigned short* nb11p = (unsigned short*)(ws + 49 * MB_);
  unsigned short* Wa10p = (unsigned short*)(ws + 57 * MB_);
  unsigned short* Wb10p = (unsigned short*)(ws + 59 * MB_);
  unsigned short* Wb11p = (unsigned short*)(ws + 61 * MB_);
  unsigned short* Wa00p = (unsigned short*)(ws + 63 * MB_);
  unsigned short* Wb00p = (unsigned short*)(ws + 66 * MB_);

  kz<<<2048, 256, 0, stream>>>((float4*)out, cnt, (long)Bn * 512);

  CvtArgs ca{};
  long gb = 0;
  auto seg = [&](int i, const float* s, unsigned short* d, int stride, int gprow, int rows) {
    ca.s[i].src = s; ca.s[i].dst = d; ca.s[i].srcStride = stride;
    ca.s[i].gprow = gprow; ca.s[i].gbase = gb;
    gb += (long)gprow * rows;
  };
  seg(0, X, Xp, 512, 64, Bn);
  seg(1, pb, pb0p, 1024, 64, Bn);
  seg(2, pb + 512, pb1p, 1024, 64, Bn);
  seg(3, pa + 512, pa1p, 1024, 64, Bn);
  seg(4, Wa10, Wa10p, 1024, 128, 512);
  seg(5, Wb10, Wb10p, 1024, 128, 512);
  seg(6, Wb11, Wb11p, 1024, 128, 512);
  seg(7, Wa00, Wa00p, 1536, 192, 512);
  seg(8, Wb00, Wb00p, 1536, 192, 512);
  ca.total = gb;
  kcvt<<<2048, 256, 0, stream>>>(ca);

  kclassify<<<(Bn + 255) / 256, 256, 0, stream>>>(pdep, dep, fo, jo, cnt, list0, list1, Bn);

  GArgs Ga;
  Ga.Xp = Xp; Ga.pb0p = pb0p; Ga.pb1p = pb1p; Ga.pa1p = pa1p;
  Ga.na10p = na10p; Ga.na00p = na00p; Ga.nb11p = nb11p;
  Ga.Wa10p = Wa10p; Ga.Wb10p = Wb10p; Ga.Wb11p = Wb11p;
  Ga.Wa00p = Wa00p; Ga.Wb00p = Wb00p;
  Ga.nextA = nextA; Ga.nextB = nextB;
  Ga.cnt = cnt; Ga.list0 = list0; Ga.list1 = list1; Ga.list2 = list2; Ga.list2i = list2i;

  // G1: fused A10 + B11 + A00 (independent, all inputs ready). 96 Mtile-groups x 8 ntiles.
  gemm_mfma<128, true><<<768, 256, 0, stream>>>(Ga, 0);

  kselect<<<Bn, 64, 0, stream>>>(pa, pb, Watt, nb11p, na00p, nextA, nextB,
                                 dep, fo, jo, cnt, list1, list2, list2i);

  gemm_mfma<64, false><<<512, 256, 0, stream>>>(Ga, 3);  // B10
  gemm_mfma<64, false><<<512, 256, 0, stream>>>(Ga, 4);  // B00
}

// Round 6
// 265.843 us; speedup vs baseline: 1.8901x; 1.8901x over previous
//
#include <hip/hip_runtime.h>
#include <hip/hip_bf16.h>
#include <stdint.h>

// LcRnnCell DEPTH=1, B=4096, E=H=512. Split-bf16 MFMA, on-the-fly conversion.
// pd==0 rows: na10=[X,b_dm1]@Wa10^T ; nb10=[X,na10]@Wb10^T ; sel forced col2.
// pd==1 rows: nb11=[X,b_d]@Wb11^T ; na00=[X,b_dm1,a_d]@Wa00^T (hoisted);
//   z from [0,a_d,b_d,0,a_d,nb11]; sel over {0,1,3};
//   sel0: nb00=[X,a_d,na00]@Wb00^T (atomicAdd later); sel1: zeros; sel3: [a_d;nb11].
// All matmuls: 3-product split-bf16 (hh+hl+lh), fp32 accumulate (validated r2).
// r6: nb-dataflow reverted to r2-proven mechanisms (na10ws buffer, split tail
// launches, atomicAdd B00 epilogue) after r5 failed output-1 only.

typedef __attribute__((ext_vector_type(8))) short bf16x8;
typedef __attribute__((ext_vector_type(4))) float f32x4;

#define MB_ ((size_t)1 << 20)

static __device__ __forceinline__ unsigned short f2bf(float x) {
  unsigned u = __float_as_uint(x);
  return (unsigned short)((u + 0x7FFFu + ((u >> 16) & 1u)) >> 16);
}
static __device__ __forceinline__ float bf2f(unsigned short b) {
  return __uint_as_float((unsigned)b << 16);
}
static __device__ __forceinline__ void cvt8(float4 v0, float4 v1, uint4& hi, uint4& lo) {
  float v[8] = {v0.x, v0.y, v0.z, v0.w, v1.x, v1.y, v1.z, v1.w};
  unsigned hw[4], lw[4];
#pragma unroll
  for (int j = 0; j < 4; ++j) {
    unsigned short h0 = f2bf(v[2 * j]), h1 = f2bf(v[2 * j + 1]);
    unsigned short l0 = f2bf(v[2 * j] - bf2f(h0));
    unsigned short l1 = f2bf(v[2 * j + 1] - bf2f(h1));
    hw[j] = (unsigned)h0 | ((unsigned)h1 << 16);
    lw[j] = (unsigned)l0 | ((unsigned)l1 << 16);
  }
  hi = make_uint4(hw[0], hw[1], hw[2], hw[3]);
  lo = make_uint4(lw[0], lw[1], lw[2], lw[3]);
}

// Zero slice-0 (k 0..511) of nextA/nextB for every row + counters.
__global__ void kinit(float* nextA, float* nextB, int* cnt, int Bn) {
  long i = (long)blockIdx.x * blockDim.x + threadIdx.x;
  long st = (long)gridDim.x * blockDim.x;
  long n4 = (long)Bn * 128;
  float4 z = make_float4(0.f, 0.f, 0.f, 0.f);
  for (long t = i; t < n4; t += st) {
    long row = t >> 7;
    int off = (int)(t & 127);
    ((float4*)(nextA + row * 1024))[off] = z;
    ((float4*)(nextB + row * 1024))[off] = z;
  }
  if (blockIdx.x == 0 && threadIdx.x < 16) cnt[threadIdx.x] = 0;
}

// Pack the 5 weights fp32 -> [row][kb][slot0..7][8 shorts] (hi slots 0-3, lo 4-7).
struct CvtSeg { const float* src; unsigned short* dst; int srcStride; int gprow; long gbase; };
struct CvtArgs { CvtSeg s[5]; long total; };

__global__ void kcvt(CvtArgs a) {
  long g0 = (long)blockIdx.x * blockDim.x + threadIdx.x;
  long st = (long)gridDim.x * blockDim.x;
  for (long g = g0; g < a.total; g += st) {
    const float* src = a.s[0].src;
    unsigned short* dst = a.s[0].dst;
    int stride = a.s[0].srcStride, gp = a.s[0].gprow;
    long base = 0;
#pragma unroll
    for (int t = 1; t < 5; ++t) {
      if (g >= a.s[t].gbase) {
        src = a.s[t].src; dst = a.s[t].dst;
        stride = a.s[t].srcStride; gp = a.s[t].gprow; base = a.s[t].gbase;
      }
    }
    long lg = g - base;
    int row = (int)(lg / gp);
    int kp = (int)(lg - (long)row * gp);
    const float* p = src + (long)row * stride + kp * 8;
    uint4 hi, lo;
    cvt8(*(const float4*)p, *(const float4*)(p + 4), hi, lo);
    unsigned short* d = dst + (long)row * ((long)gp * 16) + (long)(kp >> 2) * 64 + (kp & 3) * 8;
    *(uint4*)d = hi;
    *(uint4*)(d + 32) = lo;
  }
}

__global__ void kclassify(const int* __restrict__ pdep, float* dep, float* fo, float* jo,
                          int* cnt, int* list0, int* list1, int Bn) {
  int r = blockIdx.x * blockDim.x + threadIdx.x;
  if (r >= Bn) return;
  if (pdep[r] == 0) {
    int p = atomicAdd(&cnt[0], 1);
    list0[p] = r;
    dep[r] = 1.0f; fo[r] = 1.0f; jo[r] = 0.0f;
  } else {
    int p = atomicAdd(&cnt[1], 1);
    list1[p] = r;
  }
}

struct GArgs {
  const float *X, *pa, *pb;
  float *nb11ws, *na00ws, *na10ws;
  const unsigned short *Wa10p, *Wb10p, *Wb11p, *Wa00p, *Wb00p;
  float *nextA, *nextB;
  const int *cnt, *list0, *list1, *list2, *list2i;
};

// modes: 0=A10, 1=B11, 2=A00 (fused G1 launch); 3=B10 launch; 4=B00 launch.
// 64x64 tile, BK=32, 4 waves (2x2), double-buffered LDS, 1 barrier/K-step,
// XCD swizzle: blocks sharing an A-tile (all 8 nt) land on one XCD contiguously.
__global__ __launch_bounds__(256, 4) void gemm_mfma(GArgs G, int modeBase, int bpm) {
  int mode = (int)blockIdx.x / bpm + modeBase;
  int bl = (int)blockIdx.x % bpm;
  int xcd = bl & 7, g = bl >> 3;
  int nt = g & 7, mt = (g >> 3) * 8 + xcd;

  const int* lst; int cntv, ksteps;
  const unsigned short* W;
  if (mode == 0)      { lst = G.list0; cntv = G.cnt[0]; ksteps = 32; W = G.Wa10p; }
  else if (mode == 1) { lst = G.list1; cntv = G.cnt[1]; ksteps = 32; W = G.Wb11p; }
  else if (mode == 2) { lst = G.list1; cntv = G.cnt[1]; ksteps = 48; W = G.Wa00p; }
  else if (mode == 3) { lst = G.list0; cntv = G.cnt[0]; ksteps = 32; W = G.Wb10p; }
  else                { lst = G.list2; cntv = G.cnt[2]; ksteps = 48; W = G.Wb00p; }
  if (mt * 64 >= cntv) return;

  const int tid = threadIdx.x;
  const int arow = tid >> 2, kg = tid & 3;  // staging: 1 row x 8 k per thread (A and B)
  int mg = mt * 64 + arow;
  if (mg > cntv - 1) mg = cntv - 1;
  int r01 = lst[mg];
  const float* ab0 = G.X + (long)r01 * 512 + kg * 8;
  const float* ab1;
  const float* ab2 = nullptr;
  if (mode == 0)      ab1 = G.pb + (long)r01 * 1024 + kg * 8;              // b_dm1
  else if (mode == 1) ab1 = G.pb + (long)r01 * 1024 + 512 + kg * 8;        // b_d
  else if (mode == 2) {
    ab1 = G.pb + (long)r01 * 1024 + kg * 8;                                // b_dm1
    ab2 = G.pa + (long)r01 * 1024 + 512 + kg * 8;                          // a_d
  } else if (mode == 3) {
    ab1 = G.na10ws + (long)mg * 512 + kg * 8;                              // na10 (pos-idx ws)
  } else {
    ab1 = G.pa + (long)r01 * 1024 + 512 + kg * 8;                          // a_d
    ab2 = G.na00ws + (long)G.list2i[mg] * 512 + kg * 8;                    // na00 (pos-idx ws)
  }
  long wb = (long)(nt * 64 + arow) * (long)(ksteps * 64) + kg * 8;

  __shared__ unsigned short lds[2][2][4096];  // [buf][A/B][slot(8)][row(64)][8]

  float4 av0, av1;
  uint4 bhr, blr;
  auto gload = [&](int kb) {
    const float* p = (kb < 16) ? ab0 : (kb < 32) ? ab1 : ab2;
    p += (kb & 15) * 32;
    av0 = *(const float4*)p;
    av1 = *(const float4*)(p + 4);
    const unsigned short* q = W + wb + (long)kb * 64;
    bhr = *(const uint4*)q;
    blr = *(const uint4*)(q + 32);
  };
  auto lstore = [&](int b) {
    uint4 hi, lo;
    cvt8(av0, av1, hi, lo);
    *(uint4*)&lds[b][0][((kg) * 64 + arow) * 8] = hi;
    *(uint4*)&lds[b][0][((kg + 4) * 64 + arow) * 8] = lo;
    *(uint4*)&lds[b][1][((kg) * 64 + arow) * 8] = bhr;
    *(uint4*)&lds[b][1][((kg + 4) * 64 + arow) * 8] = blr;
  };

  const int w = tid >> 6, lane = tid & 63;
  const int wrow = (w >> 1) * 32, wcol = (w & 1) * 32;
  const int gq = lane >> 4, lr = lane & 15;

  f32x4 acc[2][2];
#pragma unroll
  for (int i = 0; i < 2; ++i)
#pragma unroll
    for (int j = 0; j < 2; ++j) acc[i][j] = (f32x4){0.f, 0.f, 0.f, 0.f};

  gload(0);
  lstore(0);
  __syncthreads();
  int cur = 0;
  for (int kb = 0; kb < ksteps; ++kb) {
    bf16x8 ah[2], al[2], bh[2], bl[2];
#pragma unroll
    for (int t = 0; t < 2; ++t) {
      ah[t] = *(const bf16x8*)&lds[cur][0][(gq * 64 + wrow + t * 16 + lr) * 8];
      al[t] = *(const bf16x8*)&lds[cur][0][((gq + 4) * 64 + wrow + t * 16 + lr) * 8];
      bh[t] = *(const bf16x8*)&lds[cur][1][(gq * 64 + wcol + t * 16 + lr) * 8];
      bl[t] = *(const bf16x8*)&lds[cur][1][((gq + 4) * 64 + wcol + t * 16 + lr) * 8];
    }
    if (kb + 1 < ksteps) gload(kb + 1);
#pragma unroll
    for (int rb = 0; rb < 2; ++rb)
#pragma unroll
      for (int cb = 0; cb < 2; ++cb) {
        acc[rb][cb] = __builtin_amdgcn_mfma_f32_16x16x32_bf16(ah[rb], bh[cb], acc[rb][cb], 0, 0, 0);
        acc[rb][cb] = __builtin_amdgcn_mfma_f32_16x16x32_bf16(ah[rb], bl[cb], acc[rb][cb], 0, 0, 0);
        acc[rb][cb] = __builtin_amdgcn_mfma_f32_16x16x32_bf16(al[rb], bh[cb], acc[rb][cb], 0, 0, 0);
      }
    if (kb + 1 < ksteps) lstore(cur ^ 1);  // safe: all waves' reads of cur^1 drained at prior barrier
    __syncthreads();
    cur ^= 1;
  }

  // epilogue: row = wrow+rb*16+(lane>>4)*4+e, col = nt*64+wcol+cb*16+lr (validated r2)
#pragma unroll
  for (int rb = 0; rb < 2; ++rb)
#pragma unroll
    for (int e = 0; e < 4; ++e) {
      int m = wrow + rb * 16 + (lane >> 4) * 4 + e;
      int mgo = mt * 64 + m;
      if (mgo >= cntv) continue;
#pragma unroll
      for (int cb = 0; cb < 2; ++cb) {
        int n = nt * 64 + wcol + cb * 16 + lr;
        float v = acc[rb][cb][e];
        if (mode == 0) {
          G.nextA[(long)G.list0[mgo] * 1024 + 512 + n] = v;
          G.na10ws[(long)mgo * 512 + n] = v;  // pos-indexed copy for B10's A-segment
        } else if (mode == 1) {
          G.nb11ws[(long)mgo * 512 + n] = v;
        } else if (mode == 2) {
          G.na00ws[(long)mgo * 512 + n] = v;
        } else if (mode == 3) {
          G.nextB[(long)G.list0[mgo] * 1024 + 512 + n] = v;
        } else {
          atomicAdd(G.nextB + (long)G.list2[mgo] * 1024 + 512 + n, v);  // nb00 onto s3*nb11
        }
      }
    }
}

// 4 warps/block, 1 pd==1 row per warp. Writes slice-1 unconditionally
// (s1-only rows get zeros). Exact softmax+sign semantics, ties additive.
__global__ __launch_bounds__(256) void kselect(
    const float* __restrict__ pa, const float* __restrict__ pb,
    const float* __restrict__ watt, const float* __restrict__ nb11ws,
    const float* __restrict__ na00ws,
    float* nextA, float* nextB, float* dep, float* fo, float* jo,
    int* cnt, const int* __restrict__ list1, int* list2, int* list2i) {
  int warp = threadIdx.x >> 6, lane = threadIdx.x & 63;
  int i1 = blockIdx.x * 4 + warp;
  if (i1 >= cnt[1]) return;
  int r = list1[i1];
  const float* a_d = pa + (long)r * 1024 + 512;
  const float* b_d = pb + (long)r * 1024 + 512;
  const float* nb = nb11ws + (long)i1 * 512;
  const float* na = na00ws + (long)i1 * 512;
  float av[8], nv[8];
  float z0 = 0.f, z1 = 0.f, z2 = 0.f, z3 = 0.f;
#pragma unroll
  for (int u = 0; u < 8; ++u) {
    int h = u * 64 + lane;
    float la = a_d[h], lb = b_d[h], ln = nb[h];
    av[u] = la; nv[u] = ln;
    z0 += (watt[1024 + h] + watt[3072 + h]) * la + watt[1536 + h] * lb + watt[3584 + h] * ln;
    z1 += (watt[5120 + h] + watt[7168 + h]) * la + watt[5632 + h] * lb + watt[7680 + h] * ln;
    z2 += (watt[9216 + h] + watt[11264 + h]) * la + watt[9728 + h] * lb + watt[11776 + h] * ln;
    z3 += (watt[13312 + h] + watt[15360 + h]) * la + watt[13824 + h] * lb + watt[15872 + h] * ln;
  }
#pragma unroll
  for (int off = 32; off; off >>= 1) {
    z0 += __shfl_xor(z0, off); z1 += __shfl_xor(z1, off);
    z2 += __shfl_xor(z2, off); z3 += __shfl_xor(z3, off);
  }
  float m = fmaxf(fmaxf(z0, z1), fmaxf(z2, z3));
  float e0 = expf(z0 - m), e1 = expf(z1 - m), e2 = expf(z2 - m), e3 = expf(z3 - m);
  float s = e0 + e1 + e2 + e3;
  float att0 = e0 / s, att1 = e1 / s, att3 = e3 / s;  // att2 masked (pd==1)
  float amax = fmaxf(att0, fmaxf(att1, att3));
  float s0 = (att0 >= amax) ? 1.f : 0.f;
  float s1v = (att1 >= amax) ? 1.f : 0.f;
  float s3 = (att3 >= amax) ? 1.f : 0.f;
  if (lane == 0) {
    dep[r] = s0 + s3;   // sel0*1 + sel1*0 + sel3*1
    fo[r] = s3;         // sel2+sel3
    jo[r] = s1v + s3;   // sel1+sel3
    if (s0 > 0.f) { int p = atomicAdd(&cnt[2], 1); list2[p] = r; list2i[p] = i1; }
  }
  float* dA = nextA + (long)r * 1024 + 512;
  float* dB = nextB + (long)r * 1024 + 512;
#pragma unroll
  for (int u = 0; u < 8; ++u) {
    int h = u * 64 + lane;
    float va = s3 * av[u];
    if (s0 > 0.f) va += na[h];
    dA[h] = va;
    dB[h] = s3 * nv[u];  // B00 atomicAdds nb00 later for sel0 rows
  }
}

extern "C" void kernel_launch(void* const* d_in, const int* in_sizes, int n_in,
                              void* d_out, int out_size, void* d_ws, size_t ws_size,
                              hipStream_t stream) {
  const float* X = (const float*)d_in[0];
  const float* pa = (const float*)d_in[1];
  const float* pb = (const float*)d_in[2];
  const int* pdep = (const int*)d_in[3];
  const float* Wa00 = (const float*)d_in[4];
  const float* Wa10 = (const float*)d_in[5];
  const float* Wb00 = (const float*)d_in[6];
  const float* Wb11 = (const float*)d_in[7];
  const float* Wb10 = (const float*)d_in[8];
  const float* Watt = (const float*)d_in[10];  // d_in[9]=Wb01 unused (nb01==0)
  const int Bn = in_sizes[3];

  float* out = (float*)d_out;
  float* nextA = out;
  float* nextB = out + (long)Bn * 1024;
  float* dep = out + (long)2 * Bn * 1024;
  float* fo = dep + Bn;
  float* jo = fo + Bn;

  char* ws = (char*)d_ws;
  int* cnt = (int*)ws;
  int* list0 = (int*)(ws + 1024);
  int* list1 = (int*)(ws + 1024 + 16384);
  int* list2 = (int*)(ws + 1024 + 2 * 16384);
  int* list2i = (int*)(ws + 1024 + 3 * 16384);
  float* nb11ws = (float*)(ws + 1 * MB_);
  float* na00ws = (float*)(ws + 9 * MB_);
  float* na10ws = (float*)(ws + 17 * MB_);
  unsigned short* Wa10p = (unsigned short*)(ws + 25 * MB_);
  unsigned short* Wb10p = (unsigned short*)(ws + 27 * MB_);
  unsigned short* Wb11p = (unsigned short*)(ws + 29 * MB_);
  unsigned short* Wa00p = (unsigned short*)(ws + 31 * MB_);
  unsigned short* Wb00p = (unsigned short*)(ws + 34 * MB_);

  kinit<<<1024, 256, 0, stream>>>(nextA, nextB, cnt, Bn);

  CvtArgs ca{};
  long gb = 0;
  auto seg = [&](int i, const float* s, unsigned short* d, int stride, int gprow, int rows) {
    ca.s[i].src = s; ca.s[i].dst = d; ca.s[i].srcStride = stride;
    ca.s[i].gprow = gprow; ca.s[i].gbase = gb;
    gb += (long)gprow * rows;
  };
  seg(0, Wa10, Wa10p, 1024, 128, 512);
  seg(1, Wb10, Wb10p, 1024, 128, 512);
  seg(2, Wb11, Wb11p, 1024, 128, 512);
  seg(3, Wa00, Wa00p, 1536, 192, 512);
  seg(4, Wb00, Wb00p, 1536, 192, 512);
  ca.total = gb;
  kcvt<<<512, 256, 0, stream>>>(ca);

  kclassify<<<(Bn + 255) / 256, 256, 0, stream>>>(pdep, dep, fo, jo, cnt, list0, list1, Bn);

  GArgs Ga;
  Ga.X = X; Ga.pa = pa; Ga.pb = pb;
  Ga.nb11ws = nb11ws; Ga.na00ws = na00ws; Ga.na10ws = na10ws;
  Ga.Wa10p = Wa10p; Ga.Wb10p = Wb10p; Ga.Wb11p = Wb11p;
  Ga.Wa00p = Wa00p; Ga.Wb00p = Wb00p;
  Ga.nextA = nextA; Ga.nextB = nextB;
  Ga.cnt = cnt; Ga.list0 = list0; Ga.list1 = list1; Ga.list2 = list2; Ga.list2i = list2i;

  int nmb = (Bn + 63) / 64;
  int nm8 = ((nmb + 7) / 8) * 8;
  int bpm = nm8 * 8;

  gemm_mfma<<<3 * bpm, 256, 0, stream>>>(Ga, 0, bpm);  // A10+B11+A00
  kselect<<<(Bn + 3) / 4, 256, 0, stream>>>(pa, pb, Watt, nb11ws, na00ws, nextA, nextB,
                                            dep, fo, jo, cnt, list1, list2, list2i);
  gemm_mfma<<<bpm, 256, 0, stream>>>(Ga, 3, bpm);      // B10
  gemm_mfma<<<bpm, 256, 0, stream>>>(Ga, 4, bpm);      // B00
}

// Round 8
// 236.865 us; speedup vs baseline: 2.1213x; 1.1223x over previous
//
#include <hip/hip_runtime.h>
#include <hip/hip_bf16.h>
#include <stdint.h>

// LcRnnCell DEPTH=1, B=4096, E=H=512. Split-bf16 MFMA, on-the-fly conversion.
// pd==0 rows: na10=[X,b_dm1]@Wa10^T ; nb10=[X,na10]@Wb10^T ; sel forced col2.
// pd==1 rows: nb11=[X,b_d]@Wb11^T ; na00=[X,b_dm1,a_d]@Wa00^T (hoisted);
//   z from [0,a_d,b_d,0,a_d,nb11]; sel over {0,1,3};
//   sel0: nb00=[X,a_d,na00]@Wb00^T (atomicAdd later); sel1: zeros; sel3: [a_d;nb11].
// Precision: B11 (feeds selection logits) = 3-product split-bf16 (hh+hl+lh).
// Other GEMMs = 2-product (A hi only: ah*bh + ah*bl), err ~1e-3 << 0.0925 thr.
// r7: LDS XOR swizzle (r6 had 8-way ds_write conflicts, 1.11e7 cyc), gload
// hoist, K-split tails (B10 x2, B00 x3) for occupancy. Dataflow = r6-proven.

typedef __attribute__((ext_vector_type(8))) short bf16x8;
typedef __attribute__((ext_vector_type(4))) float f32x4;

#define MB_ ((size_t)1 << 20)

static __device__ __forceinline__ unsigned short f2bf(float x) {
  unsigned u = __float_as_uint(x);
  return (unsigned short)((u + 0x7FFFu + ((u >> 16) & 1u)) >> 16);
}
static __device__ __forceinline__ float bf2f(unsigned short b) {
  return __uint_as_float((unsigned)b << 16);
}
static __device__ __forceinline__ void cvt8(float4 v0, float4 v1, uint4& hi, uint4& lo) {
  float v[8] = {v0.x, v0.y, v0.z, v0.w, v1.x, v1.y, v1.z, v1.w};
  unsigned hw[4], lw[4];
#pragma unroll
  for (int j = 0; j < 4; ++j) {
    unsigned short h0 = f2bf(v[2 * j]), h1 = f2bf(v[2 * j + 1]);
    unsigned short l0 = f2bf(v[2 * j] - bf2f(h0));
    unsigned short l1 = f2bf(v[2 * j + 1] - bf2f(h1));
    hw[j] = (unsigned)h0 | ((unsigned)h1 << 16);
    lw[j] = (unsigned)l0 | ((unsigned)l1 << 16);
  }
  hi = make_uint4(hw[0], hw[1], hw[2], hw[3]);
  lo = make_uint4(lw[0], lw[1], lw[2], lw[3]);
}

// Zero nextA slice0, ALL of nextB (B10 atomicAdd dest), counters.
__global__ void kinit(float* nextA, float* nextB, int* cnt, int Bn) {
  long i = (long)blockIdx.x * blockDim.x + threadIdx.x;
  long st = (long)gridDim.x * blockDim.x;
  float4 z = make_float4(0.f, 0.f, 0.f, 0.f);
  long nA = (long)Bn * 128;  // slice-0 float4s of nextA
  for (long t = i; t < nA; t += st)
    ((float4*)(nextA + (t >> 7) * 1024))[t & 127] = z;
  long nB = (long)Bn * 256;  // all of nextB
  for (long t = i; t < nB; t += st) ((float4*)nextB)[t] = z;
  if (blockIdx.x == 0 && threadIdx.x < 16) cnt[threadIdx.x] = 0;
}

// Pack the 5 weights fp32 -> [row][kb][slot0..7][8 shorts] (hi slots 0-3, lo 4-7).
struct CvtSeg { const float* src; unsigned short* dst; int srcStride; int gprow; long gbase; };
struct CvtArgs { CvtSeg s[5]; long total; };

__global__ void kcvt(CvtArgs a) {
  long g0 = (long)blockIdx.x * blockDim.x + threadIdx.x;
  long st = (long)gridDim.x * blockDim.x;
  for (long g = g0; g < a.total; g += st) {
    const float* src = a.s[0].src;
    unsigned short* dst = a.s[0].dst;
    int stride = a.s[0].srcStride, gp = a.s[0].gprow;
    long base = 0;
#pragma unroll
    for (int t = 1; t < 5; ++t) {
      if (g >= a.s[t].gbase) {
        src = a.s[t].src; dst = a.s[t].dst;
        stride = a.s[t].srcStride; gp = a.s[t].gprow; base = a.s[t].gbase;
      }
    }
    long lg = g - base;
    int row = (int)(lg / gp);
    int kp = (int)(lg - (long)row * gp);
    const float* p = src + (long)row * stride + kp * 8;
    uint4 hi, lo;
    cvt8(*(const float4*)p, *(const float4*)(p + 4), hi, lo);
    unsigned short* d = dst + (long)row * ((long)gp * 16) + (long)(kp >> 2) * 64 + (kp & 3) * 8;
    *(uint4*)d = hi;
    *(uint4*)(d + 32) = lo;
  }
}

__global__ void kclassify(const int* __restrict__ pdep, float* dep, float* fo, float* jo,
                          int* cnt, int* list0, int* list1, int Bn) {
  int r = blockIdx.x * blockDim.x + threadIdx.x;
  if (r >= Bn) return;
  if (pdep[r] == 0) {
    int p = atomicAdd(&cnt[0], 1);
    list0[p] = r;
    dep[r] = 1.0f; fo[r] = 1.0f; jo[r] = 0.0f;
  } else {
    int p = atomicAdd(&cnt[1], 1);
    list1[p] = r;
  }
}

struct GArgs {
  const float *X, *pa, *pb;
  float *nb11ws, *na00ws, *na10ws;
  const unsigned short *Wa10p, *Wb10p, *Wb11p, *Wa00p, *Wb00p;
  float *nextA, *nextB;
  const int *cnt, *list0, *list1, *list2, *list2i;
};

// modes: 0=A10, 1=B11, 2=A00 (fused G1 launch); 3=B10 (ksplit 2); 4=B00 (ksplit 3).
// 64x64 tile, BK=32, 4 waves (2x2), double-buffered LDS, 1 barrier/K-step.
// XCD swizzle: 8 nt-blocks sharing an A-tile land on one XCD contiguously.
// LDS index: unit = slot*64 + (row ^ slot)  [XOR swizzle, write+read both sides].
__global__ __launch_bounds__(256, 4) void gemm_mfma(GArgs G, int modeBase, int bpm) {
  int grp = (int)blockIdx.x / bpm;
  int bl = (int)blockIdx.x % bpm;
  int mode, ks;
  if (modeBase == 0) { mode = grp; ks = 0; }
  else { mode = modeBase; ks = grp; }
  int xcd = bl & 7, g = bl >> 3;
  int nt = g & 7, mt = (g >> 3) * 8 + xcd;

  const int* lst; int cntv, ktot;
  const unsigned short* W;
  if (mode == 0)      { lst = G.list0; cntv = G.cnt[0]; ktot = 32; W = G.Wa10p; }
  else if (mode == 1) { lst = G.list1; cntv = G.cnt[1]; ktot = 32; W = G.Wb11p; }
  else if (mode == 2) { lst = G.list1; cntv = G.cnt[1]; ktot = 48; W = G.Wa00p; }
  else if (mode == 3) { lst = G.list0; cntv = G.cnt[0]; ktot = 32; W = G.Wb10p; }
  else                { lst = G.list2; cntv = G.cnt[2]; ktot = 48; W = G.Wb00p; }
  if (mt * 64 >= cntv) return;
  const bool full3 = (mode == 1);  // 3-product only for selection-critical B11
  const int kb0 = ks * 16;
  const int kb1 = (modeBase == 0) ? ktot : kb0 + 16;

  const int tid = threadIdx.x;
  const int arow = tid >> 2, kg = tid & 3;  // staging: 1 row x 8 k per thread
  int mg = mt * 64 + arow;
  if (mg > cntv - 1) mg = cntv - 1;
  int r01 = lst[mg];
  const float* ab0 = G.X + (long)r01 * 512 + kg * 8;
  const float* ab1;
  const float* ab2 = nullptr;
  if (mode == 0)      ab1 = G.pb + (long)r01 * 1024 + kg * 8;              // b_dm1
  else if (mode == 1) ab1 = G.pb + (long)r01 * 1024 + 512 + kg * 8;        // b_d
  else if (mode == 2) {
    ab1 = G.pb + (long)r01 * 1024 + kg * 8;                                // b_dm1
    ab2 = G.pa + (long)r01 * 1024 + 512 + kg * 8;                          // a_d
  } else if (mode == 3) {
    ab1 = G.na10ws + (long)mg * 512 + kg * 8;                              // na10 (pos-idx ws)
  } else {
    ab1 = G.pa + (long)r01 * 1024 + 512 + kg * 8;                          // a_d
    ab2 = G.na00ws + (long)G.list2i[mg] * 512 + kg * 8;                    // na00 (pos-idx ws)
  }
  long wb = (long)(nt * 64 + arow) * (long)(ktot * 64) + kg * 8;

  __shared__ unsigned short lds[2][2][4096];  // [buf][A/B][swizzled unit][8]

  float4 av0, av1;
  uint4 bhr, blr;
  auto gload = [&](int kb) {
    const float* p = (kb < 16) ? ab0 : (kb < 32) ? ab1 : ab2;
    p += (kb & 15) * 32;
    av0 = *(const float4*)p;
    av1 = *(const float4*)(p + 4);
    const unsigned short* q = W + wb + (long)kb * 64;
    bhr = *(const uint4*)q;
    blr = *(const uint4*)(q + 32);
  };
  auto lstore = [&](int b) {
    uint4 hi, lo;
    cvt8(av0, av1, hi, lo);
    *(uint4*)&lds[b][0][(kg * 64 + (arow ^ kg)) * 8] = hi;
    if (full3)
      *(uint4*)&lds[b][0][((kg + 4) * 64 + (arow ^ (kg + 4))) * 8] = lo;
    *(uint4*)&lds[b][1][(kg * 64 + (arow ^ kg)) * 8] = bhr;
    *(uint4*)&lds[b][1][((kg + 4) * 64 + (arow ^ (kg + 4))) * 8] = blr;
  };

  const int w = tid >> 6, lane = tid & 63;
  const int wrow = (w >> 1) * 32, wcol = (w & 1) * 32;
  const int gq = lane >> 4, lr = lane & 15;

  f32x4 acc[2][2];
#pragma unroll
  for (int i = 0; i < 2; ++i)
#pragma unroll
    for (int j = 0; j < 2; ++j) acc[i][j] = (f32x4){0.f, 0.f, 0.f, 0.f};

  gload(kb0);
  lstore(0);
  __syncthreads();
  int cur = 0;
  for (int kb = kb0; kb < kb1; ++kb) {
    if (kb + 1 < kb1) gload(kb + 1);  // hoisted: vmcnt drain hides under reads+MFMA
    bf16x8 ah[2], al[2], bh[2], bl[2];
#pragma unroll
    for (int t = 0; t < 2; ++t) {
      int rr = wrow + t * 16 + lr, cc = wcol + t * 16 + lr;
      ah[t] = *(const bf16x8*)&lds[cur][0][(gq * 64 + (rr ^ gq)) * 8];
      bh[t] = *(const bf16x8*)&lds[cur][1][(gq * 64 + (cc ^ gq)) * 8];
      bl[t] = *(const bf16x8*)&lds[cur][1][((gq + 4) * 64 + (cc ^ (gq + 4))) * 8];
      if (full3)
        al[t] = *(const bf16x8*)&lds[cur][0][((gq + 4) * 64 + (rr ^ (gq + 4))) * 8];
    }
#pragma unroll
    for (int rb = 0; rb < 2; ++rb)
#pragma unroll
      for (int cb = 0; cb < 2; ++cb) {
        acc[rb][cb] = __builtin_amdgcn_mfma_f32_16x16x32_bf16(ah[rb], bh[cb], acc[rb][cb], 0, 0, 0);
        acc[rb][cb] = __builtin_amdgcn_mfma_f32_16x16x32_bf16(ah[rb], bl[cb], acc[rb][cb], 0, 0, 0);
        if (full3)
          acc[rb][cb] = __builtin_amdgcn_mfma_f32_16x16x32_bf16(al[rb], bh[cb], acc[rb][cb], 0, 0, 0);
      }
    if (kb + 1 < kb1) lstore(cur ^ 1);  // safe: cur^1 reads drained at prior barrier
    __syncthreads();
    cur ^= 1;
  }

  // epilogue: row = wrow+rb*16+(lane>>4)*4+e, col = nt*64+wcol+cb*16+lr (validated r2/r6)
#pragma unroll
  for (int rb = 0; rb < 2; ++rb)
#pragma unroll
    for (int e = 0; e < 4; ++e) {
      int m = wrow + rb * 16 + (lane >> 4) * 4 + e;
      int mgo = mt * 64 + m;
      if (mgo >= cntv) continue;
#pragma unroll
      for (int cb = 0; cb < 2; ++cb) {
        int n = nt * 64 + wcol + cb * 16 + lr;
        float v = acc[rb][cb][e];
        if (mode == 0) {
          G.nextA[(long)G.list0[mgo] * 1024 + 512 + n] = v;
          G.na10ws[(long)mgo * 512 + n] = v;  // pos-indexed copy for B10's A-segment
        } else if (mode == 1) {
          G.nb11ws[(long)mgo * 512 + n] = v;
        } else if (mode == 2) {
          G.na00ws[(long)mgo * 512 + n] = v;
        } else {
          // modes 3,4: K-split partials; dest zeroed (B10) / kselect-written (B00)
          atomicAdd(G.nextB + (long)lst[mgo] * 1024 + 512 + n, v);
        }
      }
    }
}

// 4 warps/block, 1 pd==1 row per warp. Writes slice-1 unconditionally
// (s1-only rows get zeros). Exact softmax+sign semantics, ties additive.
__global__ __launch_bounds__(256) void kselect(
    const float* __restrict__ pa, const float* __restrict__ pb,
    const float* __restrict__ watt, const float* __restrict__ nb11ws,
    const float* __restrict__ na00ws,
    float* nextA, float* nextB, float* dep, float* fo, float* jo,
    int* cnt, const int* __restrict__ list1, int* list2, int* list2i) {
  int warp = threadIdx.x >> 6, lane = threadIdx.x & 63;
  int i1 = blockIdx.x * 4 + warp;
  if (i1 >= cnt[1]) return;
  int r = list1[i1];
  const float* a_d = pa + (long)r * 1024 + 512;
  const float* b_d = pb + (long)r * 1024 + 512;
  const float* nb = nb11ws + (long)i1 * 512;
  const float* na = na00ws + (long)i1 * 512;
  float av[8], nv[8];
  float z0 = 0.f, z1 = 0.f, z2 = 0.f, z3 = 0.f;
#pragma unroll
  for (int u = 0; u < 8; ++u) {
    int h = u * 64 + lane;
    float la = a_d[h], lb = b_d[h], ln = nb[h];
    av[u] = la; nv[u] = ln;
    z0 += (watt[1024 + h] + watt[3072 + h]) * la + watt[1536 + h] * lb + watt[3584 + h] * ln;
    z1 += (watt[5120 + h] + watt[7168 + h]) * la + watt[5632 + h] * lb + watt[7680 + h] * ln;
    z2 += (watt[9216 + h] + watt[11264 + h]) * la + watt[9728 + h] * lb + watt[11776 + h] * ln;
    z3 += (watt[13312 + h] + watt[15360 + h]) * la + watt[13824 + h] * lb + watt[15872 + h] * ln;
  }
#pragma unroll
  for (int off = 32; off; off >>= 1) {
    z0 += __shfl_xor(z0, off); z1 += __shfl_xor(z1, off);
    z2 += __shfl_xor(z2, off); z3 += __shfl_xor(z3, off);
  }
  float m = fmaxf(fmaxf(z0, z1), fmaxf(z2, z3));
  float e0 = expf(z0 - m), e1 = expf(z1 - m), e2 = expf(z2 - m), e3 = expf(z3 - m);
  float s = e0 + e1 + e2 + e3;
  float att0 = e0 / s, att1 = e1 / s, att3 = e3 / s;  // att2 masked (pd==1)
  float amax = fmaxf(att0, fmaxf(att1, att3));
  float s0 = (att0 >= amax) ? 1.f : 0.f;
  float s1v = (att1 >= amax) ? 1.f : 0.f;
  float s3 = (att3 >= amax) ? 1.f : 0.f;
  if (lane == 0) {
    dep[r] = s0 + s3;   // sel0*1 + sel1*0 + sel3*1
    fo[r] = s3;         // sel2+sel3
    jo[r] = s1v + s3;   // sel1+sel3
    if (s0 > 0.f) { int p = atomicAdd(&cnt[2], 1); list2[p] = r; list2i[p] = i1; }
  }
  float* dA = nextA + (long)r * 1024 + 512;
  float* dB = nextB + (long)r * 1024 + 512;
#pragma unroll
  for (int u = 0; u < 8; ++u) {
    int h = u * 64 + lane;
    float va = s3 * av[u];
    if (s0 > 0.f) va += na[h];
    dA[h] = va;
    dB[h] = s3 * nv[u];  // B00 atomicAdds nb00 later for sel0 rows
  }
}

extern "C" void kernel_launch(void* const* d_in, const int* in_sizes, int n_in,
                              void* d_out, int out_size, void* d_ws, size_t ws_size,
                              hipStream_t stream) {
  const float* X = (const float*)d_in[0];
  const float* pa = (const float*)d_in[1];
  const float* pb = (const float*)d_in[2];
  const int* pdep = (const int*)d_in[3];
  const float* Wa00 = (const float*)d_in[4];
  const float* Wa10 = (const float*)d_in[5];
  const float* Wb00 = (const float*)d_in[6];
  const float* Wb11 = (const float*)d_in[7];
  const float* Wb10 = (const float*)d_in[8];
  const float* Watt = (const float*)d_in[10];  // d_in[9]=Wb01 unused (nb01==0)
  const int Bn = in_sizes[3];

  float* out = (float*)d_out;
  float* nextA = out;
  float* nextB = out + (long)Bn * 1024;
  float* dep = out + (long)2 * Bn * 1024;
  float* fo = dep + Bn;
  float* jo = fo + Bn;

  char* ws = (char*)d_ws;
  int* cnt = (int*)ws;
  int* list0 = (int*)(ws + 1024);
  int* list1 = (int*)(ws + 1024 + 16384);
  int* list2 = (int*)(ws + 1024 + 2 * 16384);
  int* list2i = (int*)(ws + 1024 + 3 * 16384);
  float* nb11ws = (float*)(ws + 1 * MB_);
  float* na00ws = (float*)(ws + 9 * MB_);
  float* na10ws = (float*)(ws + 17 * MB_);
  unsigned short* Wa10p = (unsigned short*)(ws + 25 * MB_);
  unsigned short* Wb10p = (unsigned short*)(ws + 27 * MB_);
  unsigned short* Wb11p = (unsigned short*)(ws + 29 * MB_);
  unsigned short* Wa00p = (unsigned short*)(ws + 31 * MB_);
  unsigned short* Wb00p = (unsigned short*)(ws + 34 * MB_);

  kinit<<<1024, 256, 0, stream>>>(nextA, nextB, cnt, Bn);

  CvtArgs ca{};
  long gb = 0;
  auto seg = [&](int i, const float* s, unsigned short* d, int stride, int gprow, int rows) {
    ca.s[i].src = s; ca.s[i].dst = d; ca.s[i].srcStride = stride;
    ca.s[i].gprow = gprow; ca.s[i].gbase = gb;
    gb += (long)gprow * rows;
  };
  seg(0, Wa10, Wa10p, 1024, 128, 512);
  seg(1, Wb10, Wb10p, 1024, 128, 512);
  seg(2, Wb11, Wb11p, 1024, 128, 512);
  seg(3, Wa00, Wa00p, 1536, 192, 512);
  seg(4, Wb00, Wb00p, 1536, 192, 512);
  ca.total = gb;
  kcvt<<<512, 256, 0, stream>>>(ca);

  kclassify<<<(Bn + 255) / 256, 256, 0, stream>>>(pdep, dep, fo, jo, cnt, list0, list1, Bn);

  GArgs Ga;
  Ga.X = X; Ga.pa = pa; Ga.pb = pb;
  Ga.nb11ws = nb11ws; Ga.na00ws = na00ws; Ga.na10ws = na10ws;
  Ga.Wa10p = Wa10p; Ga.Wb10p = Wb10p; Ga.Wb11p = Wb11p;
  Ga.Wa00p = Wa00p; Ga.Wb00p = Wb00p;
  Ga.nextA = nextA; Ga.nextB = nextB;
  Ga.cnt = cnt; Ga.list0 = list0; Ga.list1 = list1; Ga.list2 = list2; Ga.list2i = list2i;

  int nmb = (Bn + 63) / 64;
  int nm8 = ((nmb + 7) / 8) * 8;
  int bpm = nm8 * 8;

  gemm_mfma<<<3 * bpm, 256, 0, stream>>>(Ga, 0, bpm);  // G1: A10+B11+A00
  kselect<<<(Bn + 3) / 4, 256, 0, stream>>>(pa, pb, Watt, nb11ws, na00ws, nextA, nextB,
                                            dep, fo, jo, cnt, list1, list2, list2i);
  gemm_mfma<<<2 * bpm, 256, 0, stream>>>(Ga, 3, bpm);  // B10, K-split 2
  gemm_mfma<<<3 * bpm, 256, 0, stream>>>(Ga, 4, bpm);  // B00, K-split 3
}

// Round 9
// 226.429 us; speedup vs baseline: 2.2191x; 1.0461x over previous
//
#include <hip/hip_runtime.h>
#include <hip/hip_bf16.h>
#include <stdint.h>

// LcRnnCell DEPTH=1, B=4096, E=H=512. Split-bf16 MFMA, on-the-fly conversion.
// pd==0 rows: na10=[X,b_dm1]@Wa10^T ; nb10=[X,na10]@Wb10^T ; sel forced col2.
// pd==1 rows: nb11=[X,b_d]@Wb11^T ; na00=[X,b_dm1,a_d]@Wa00^T (hoisted);
//   z from [0,a_d,b_d,0,a_d,nb11]; sel over {0,1,3};
//   sel0: nb00=[X,a_d,na00]@Wb00^T (atomicAdd later); sel1: zeros; sel3: [a_d;nb11].
// Precision: B11 (feeds selection logits) = 3-product split-bf16 (hh+hl+lh);
// others 2-product (ah*bh + ah*bl), err ~1e-3 << 0.0925 thr. (r8-proven)
// r9: 2-deep register prefetch (r8 was latency-bound: 1370 cyc/block-step vs
// ~400 of work), kprep fusion (kinit+kcvt+kclassify; cnt via hipMemsetAsync).

typedef __attribute__((ext_vector_type(8))) short bf16x8;
typedef __attribute__((ext_vector_type(4))) float f32x4;

#define MB_ ((size_t)1 << 20)

static __device__ __forceinline__ unsigned short f2bf(float x) {
  unsigned u = __float_as_uint(x);
  return (unsigned short)((u + 0x7FFFu + ((u >> 16) & 1u)) >> 16);
}
static __device__ __forceinline__ float bf2f(unsigned short b) {
  return __uint_as_float((unsigned)b << 16);
}
static __device__ __forceinline__ void cvt8(float4 v0, float4 v1, uint4& hi, uint4& lo) {
  float v[8] = {v0.x, v0.y, v0.z, v0.w, v1.x, v1.y, v1.z, v1.w};
  unsigned hw[4], lw[4];
#pragma unroll
  for (int j = 0; j < 4; ++j) {
    unsigned short h0 = f2bf(v[2 * j]), h1 = f2bf(v[2 * j + 1]);
    unsigned short l0 = f2bf(v[2 * j] - bf2f(h0));
    unsigned short l1 = f2bf(v[2 * j + 1] - bf2f(h1));
    hw[j] = (unsigned)h0 | ((unsigned)h1 << 16);
    lw[j] = (unsigned)l0 | ((unsigned)l1 << 16);
  }
  hi = make_uint4(hw[0], hw[1], hw[2], hw[3]);
  lo = make_uint4(lw[0], lw[1], lw[2], lw[3]);
}

struct CvtSeg { const float* src; unsigned short* dst; int srcStride; int gprow; long gbase; };
struct CvtArgs { CvtSeg s[5]; long total; };

// Fused prep: blocks [0,512) zero nextA slice0 + all nextB; [512,1024) pack the
// 5 weights fp32 -> [row][kb][slot0..7][8] (hi 0-3, lo 4-7); [1024,1040) classify.
// cnt[] is zeroed by hipMemsetAsync BEFORE this launch (block order undefined).
__global__ __launch_bounds__(256) void kprep(float* nextA, float* nextB, CvtArgs a,
                                             const int* __restrict__ pdep, float* dep,
                                             float* fo, float* jo, int* cnt,
                                             int* list0, int* list1, int Bn) {
  int b = blockIdx.x, tid = threadIdx.x;
  if (b < 512) {
    long i = (long)b * 256 + tid;
    const long st = 512 * 256;
    float4 z = make_float4(0.f, 0.f, 0.f, 0.f);
    long nA = (long)Bn * 128;  // slice-0 float4s of nextA
    for (long t = i; t < nA; t += st)
      ((float4*)(nextA + (t >> 7) * 1024))[t & 127] = z;
    long nB = (long)Bn * 256;  // all of nextB (B10 atomicAdd dest)
    for (long t = i; t < nB; t += st) ((float4*)nextB)[t] = z;
  } else if (b < 1024) {
    long g0 = (long)(b - 512) * 256 + tid;
    const long st = 512 * 256;
    for (long g = g0; g < a.total; g += st) {
      const float* src = a.s[0].src;
      unsigned short* dst = a.s[0].dst;
      int stride = a.s[0].srcStride, gp = a.s[0].gprow;
      long base = 0;
#pragma unroll
      for (int t = 1; t < 5; ++t) {
        if (g >= a.s[t].gbase) {
          src = a.s[t].src; dst = a.s[t].dst;
          stride = a.s[t].srcStride; gp = a.s[t].gprow; base = a.s[t].gbase;
        }
      }
      long lg = g - base;
      int row = (int)(lg / gp);
      int kp = (int)(lg - (long)row * gp);
      const float* p = src + (long)row * stride + kp * 8;
      uint4 hi, lo;
      cvt8(*(const float4*)p, *(const float4*)(p + 4), hi, lo);
      unsigned short* d = dst + (long)row * ((long)gp * 16) + (long)(kp >> 2) * 64 + (kp & 3) * 8;
      *(uint4*)d = hi;
      *(uint4*)(d + 32) = lo;
    }
  } else {
    int r = (b - 1024) * 256 + tid;
    if (r >= Bn) return;
    if (pdep[r] == 0) {
      int p = atomicAdd(&cnt[0], 1);
      list0[p] = r;
      dep[r] = 1.0f; fo[r] = 1.0f; jo[r] = 0.0f;
    } else {
      int p = atomicAdd(&cnt[1], 1);
      list1[p] = r;
    }
  }
}

struct GArgs {
  const float *X, *pa, *pb;
  float *nb11ws, *na00ws, *na10ws;
  const unsigned short *Wa10p, *Wb10p, *Wb11p, *Wa00p, *Wb00p;
  float *nextA, *nextB;
  const int *cnt, *list0, *list1, *list2, *list2i;
};

// modes: 0=A10, 1=B11, 2=A00 (fused G1 launch); 3=B10 (ksplit 2); 4=B00 (ksplit 3).
// 64x64 tile, BK=32, 4 waves (2x2), double-buffered LDS, 1 barrier/K-step,
// 2-deep register prefetch (named stages, loop unrolled x2 -> static indexing).
// XCD swizzle: 8 nt-blocks sharing an A-tile land on one XCD contiguously.
// LDS unit = slot*64 + (row ^ slot) (XOR swizzle both sides, r8-proven).
__global__ __launch_bounds__(256, 4) void gemm_mfma(GArgs G, int modeBase, int bpm) {
  int grp = (int)blockIdx.x / bpm;
  int bl = (int)blockIdx.x % bpm;
  int mode, ks;
  if (modeBase == 0) { mode = grp; ks = 0; }
  else { mode = modeBase; ks = grp; }
  int xcd = bl & 7, g = bl >> 3;
  int nt = g & 7, mt = (g >> 3) * 8 + xcd;

  const int* lst; int cntv, ktot;
  const unsigned short* W;
  if (mode == 0)      { lst = G.list0; cntv = G.cnt[0]; ktot = 32; W = G.Wa10p; }
  else if (mode == 1) { lst = G.list1; cntv = G.cnt[1]; ktot = 32; W = G.Wb11p; }
  else if (mode == 2) { lst = G.list1; cntv = G.cnt[1]; ktot = 48; W = G.Wa00p; }
  else if (mode == 3) { lst = G.list0; cntv = G.cnt[0]; ktot = 32; W = G.Wb10p; }
  else                { lst = G.list2; cntv = G.cnt[2]; ktot = 48; W = G.Wb00p; }
  if (mt * 64 >= cntv) return;
  const bool full3 = (mode == 1);  // 3-product only for selection-critical B11
  const int kb0 = ks * 16;
  const int kb1 = (modeBase == 0) ? ktot : kb0 + 16;

  const int tid = threadIdx.x;
  const int arow = tid >> 2, kg = tid & 3;  // staging: 1 row x 8 k per thread
  int mg = mt * 64 + arow;
  if (mg > cntv - 1) mg = cntv - 1;
  int r01 = lst[mg];
  const float* ab0 = G.X + (long)r01 * 512 + kg * 8;
  const float* ab1;
  const float* ab2 = nullptr;
  if (mode == 0)      ab1 = G.pb + (long)r01 * 1024 + kg * 8;              // b_dm1
  else if (mode == 1) ab1 = G.pb + (long)r01 * 1024 + 512 + kg * 8;        // b_d
  else if (mode == 2) {
    ab1 = G.pb + (long)r01 * 1024 + kg * 8;                                // b_dm1
    ab2 = G.pa + (long)r01 * 1024 + 512 + kg * 8;                          // a_d
  } else if (mode == 3) {
    ab1 = G.na10ws + (long)mg * 512 + kg * 8;                              // na10 (pos-idx ws)
  } else {
    ab1 = G.pa + (long)r01 * 1024 + 512 + kg * 8;                          // a_d
    ab2 = G.na00ws + (long)G.list2i[mg] * 512 + kg * 8;                    // na00 (pos-idx ws)
  }
  long wb = (long)(nt * 64 + arow) * (long)(ktot * 64) + kg * 8;

  __shared__ unsigned short lds[2][2][4096];  // [buf][A/B][swizzled unit][8]

  auto gload = [&](int kb, float4& v0, float4& v1, uint4& bh_, uint4& bl_) {
    const float* p = (kb < 16) ? ab0 : (kb < 32) ? ab1 : ab2;
    p += (kb & 15) * 32;
    v0 = *(const float4*)p;
    v1 = *(const float4*)(p + 4);
    const unsigned short* q = W + wb + (long)kb * 64;
    bh_ = *(const uint4*)q;
    bl_ = *(const uint4*)(q + 32);
  };
  auto lstore = [&](int b, float4 v0, float4 v1, uint4 bh_, uint4 bl_) {
    uint4 hi, lo;
    cvt8(v0, v1, hi, lo);
    *(uint4*)&lds[b][0][(kg * 64 + (arow ^ kg)) * 8] = hi;
    if (full3)
      *(uint4*)&lds[b][0][((kg + 4) * 64 + (arow ^ (kg + 4))) * 8] = lo;
    *(uint4*)&lds[b][1][(kg * 64 + (arow ^ kg)) * 8] = bh_;
    *(uint4*)&lds[b][1][((kg + 4) * 64 + (arow ^ (kg + 4))) * 8] = bl_;
  };

  const int w = tid >> 6, lane = tid & 63;
  const int wrow = (w >> 1) * 32, wcol = (w & 1) * 32;
  const int gq = lane >> 4, lr = lane & 15;

  f32x4 acc[2][2];
#pragma unroll
  for (int i = 0; i < 2; ++i)
#pragma unroll
    for (int j = 0; j < 2; ++j) acc[i][j] = (f32x4){0.f, 0.f, 0.f, 0.f};

  auto compute = [&](int b) {
    bf16x8 ah[2], al[2], bh[2], bl[2];
#pragma unroll
    for (int t = 0; t < 2; ++t) {
      int rr = wrow + t * 16 + lr, cc = wcol + t * 16 + lr;
      ah[t] = *(const bf16x8*)&lds[b][0][(gq * 64 + (rr ^ gq)) * 8];
      bh[t] = *(const bf16x8*)&lds[b][1][(gq * 64 + (cc ^ gq)) * 8];
      bl[t] = *(const bf16x8*)&lds[b][1][((gq + 4) * 64 + (cc ^ (gq + 4))) * 8];
      if (full3)
        al[t] = *(const bf16x8*)&lds[b][0][((gq + 4) * 64 + (rr ^ (gq + 4))) * 8];
    }
#pragma unroll
    for (int rb = 0; rb < 2; ++rb)
#pragma unroll
      for (int cb = 0; cb < 2; ++cb) {
        acc[rb][cb] = __builtin_amdgcn_mfma_f32_16x16x32_bf16(ah[rb], bh[cb], acc[rb][cb], 0, 0, 0);
        acc[rb][cb] = __builtin_amdgcn_mfma_f32_16x16x32_bf16(ah[rb], bl[cb], acc[rb][cb], 0, 0, 0);
        if (full3)
          acc[rb][cb] = __builtin_amdgcn_mfma_f32_16x16x32_bf16(al[rb], bh[cb], acc[rb][cb], 0, 0, 0);
      }
  };

  // 2-deep pipeline: stage s0/s1 named explicitly (no runtime-indexed reg arrays).
  float4 s0a0, s0a1, s1a0, s1a1;
  uint4 s0bh, s0bl, s1bh, s1bl;
  gload(kb0, s0a0, s0a1, s0bh, s0bl);
  if (kb0 + 1 < kb1) gload(kb0 + 1, s1a0, s1a1, s1bh, s1bl);
  lstore(0, s0a0, s0a1, s0bh, s0bl);
  __syncthreads();
  int cur = 0;
  for (int kb = kb0; kb < kb1; kb += 2) {
    // even sub-step: consume lds[cur] (tile kb); store tile kb+1 from s1; refill s0 with kb+2
    if (kb + 2 < kb1) gload(kb + 2, s0a0, s0a1, s0bh, s0bl);
    if (kb + 1 < kb1) lstore(cur ^ 1, s1a0, s1a1, s1bh, s1bl);  // loads landed 1 iter ago
    compute(cur);
    __syncthreads();
    cur ^= 1;
    if (kb + 1 >= kb1) break;
    // odd sub-step: consume tile kb+1; store kb+2 from s0; refill s1 with kb+3
    if (kb + 3 < kb1) gload(kb + 3, s1a0, s1a1, s1bh, s1bl);
    if (kb + 2 < kb1) lstore(cur ^ 1, s0a0, s0a1, s0bh, s0bl);
    compute(cur);
    __syncthreads();
    cur ^= 1;
  }

  // epilogue: row = wrow+rb*16+(lane>>4)*4+e, col = nt*64+wcol+cb*16+lr (validated r2/r6/r8)
#pragma unroll
  for (int rb = 0; rb < 2; ++rb)
#pragma unroll
    for (int e = 0; e < 4; ++e) {
      int m = wrow + rb * 16 + (lane >> 4) * 4 + e;
      int mgo = mt * 64 + m;
      if (mgo >= cntv) continue;
#pragma unroll
      for (int cb = 0; cb < 2; ++cb) {
        int n = nt * 64 + wcol + cb * 16 + lr;
        float v = acc[rb][cb][e];
        if (mode == 0) {
          G.nextA[(long)G.list0[mgo] * 1024 + 512 + n] = v;
          G.na10ws[(long)mgo * 512 + n] = v;  // pos-indexed copy for B10's A-segment
        } else if (mode == 1) {
          G.nb11ws[(long)mgo * 512 + n] = v;
        } else if (mode == 2) {
          G.na00ws[(long)mgo * 512 + n] = v;
        } else {
          // modes 3,4: K-split partials; dest zeroed (B10) / kselect-written (B00)
          atomicAdd(G.nextB + (long)lst[mgo] * 1024 + 512 + n, v);
        }
      }
    }
}

// 4 warps/block, 1 pd==1 row per warp. Writes slice-1 unconditionally
// (s1-only rows get zeros). Exact softmax+sign semantics, ties additive.
__global__ __launch_bounds__(256) void kselect(
    const float* __restrict__ pa, const float* __restrict__ pb,
    const float* __restrict__ watt, const float* __restrict__ nb11ws,
    const float* __restrict__ na00ws,
    float* nextA, float* nextB, float* dep, float* fo, float* jo,
    int* cnt, const int* __restrict__ list1, int* list2, int* list2i) {
  int warp = threadIdx.x >> 6, lane = threadIdx.x & 63;
  int i1 = blockIdx.x * 4 + warp;
  if (i1 >= cnt[1]) return;
  int r = list1[i1];
  const float* a_d = pa + (long)r * 1024 + 512;
  const float* b_d = pb + (long)r * 1024 + 512;
  const float* nb = nb11ws + (long)i1 * 512;
  const float* na = na00ws + (long)i1 * 512;
  float av[8], nv[8];
  float z0 = 0.f, z1 = 0.f, z2 = 0.f, z3 = 0.f;
#pragma unroll
  for (int u = 0; u < 8; ++u) {
    int h = u * 64 + lane;
    float la = a_d[h], lb = b_d[h], ln = nb[h];
    av[u] = la; nv[u] = ln;
    z0 += (watt[1024 + h] + watt[3072 + h]) * la + watt[1536 + h] * lb + watt[3584 + h] * ln;
    z1 += (watt[5120 + h] + watt[7168 + h]) * la + watt[5632 + h] * lb + watt[7680 + h] * ln;
    z2 += (watt[9216 + h] + watt[11264 + h]) * la + watt[9728 + h] * lb + watt[11776 + h] * ln;
    z3 += (watt[13312 + h] + watt[15360 + h]) * la + watt[13824 + h] * lb + watt[15872 + h] * ln;
  }
#pragma unroll
  for (int off = 32; off; off >>= 1) {
    z0 += __shfl_xor(z0, off); z1 += __shfl_xor(z1, off);
    z2 += __shfl_xor(z2, off); z3 += __shfl_xor(z3, off);
  }
  float m = fmaxf(fmaxf(z0, z1), fmaxf(z2, z3));
  float e0 = expf(z0 - m), e1 = expf(z1 - m), e2 = expf(z2 - m), e3 = expf(z3 - m);
  float s = e0 + e1 + e2 + e3;
  float att0 = e0 / s, att1 = e1 / s, att3 = e3 / s;  // att2 masked (pd==1)
  float amax = fmaxf(att0, fmaxf(att1, att3));
  float s0 = (att0 >= amax) ? 1.f : 0.f;
  float s1v = (att1 >= amax) ? 1.f : 0.f;
  float s3 = (att3 >= amax) ? 1.f : 0.f;
  if (lane == 0) {
    dep[r] = s0 + s3;   // sel0*1 + sel1*0 + sel3*1
    fo[r] = s3;         // sel2+sel3
    jo[r] = s1v + s3;   // sel1+sel3
    if (s0 > 0.f) { int p = atomicAdd(&cnt[2], 1); list2[p] = r; list2i[p] = i1; }
  }
  float* dA = nextA + (long)r * 1024 + 512;
  float* dB = nextB + (long)r * 1024 + 512;
#pragma unroll
  for (int u = 0; u < 8; ++u) {
    int h = u * 64 + lane;
    float va = s3 * av[u];
    if (s0 > 0.f) va += na[h];
    dA[h] = va;
    dB[h] = s3 * nv[u];  // B00 atomicAdds nb00 later for sel0 rows
  }
}

extern "C" void kernel_launch(void* const* d_in, const int* in_sizes, int n_in,
                              void* d_out, int out_size, void* d_ws, size_t ws_size,
                              hipStream_t stream) {
  const float* X = (const float*)d_in[0];
  const float* pa = (const float*)d_in[1];
  const float* pb = (const float*)d_in[2];
  const int* pdep = (const int*)d_in[3];
  const float* Wa00 = (const float*)d_in[4];
  const float* Wa10 = (const float*)d_in[5];
  const float* Wb00 = (const float*)d_in[6];
  const float* Wb11 = (const float*)d_in[7];
  const float* Wb10 = (const float*)d_in[8];
  const float* Watt = (const float*)d_in[10];  // d_in[9]=Wb01 unused (nb01==0)
  const int Bn = in_sizes[3];

  float* out = (float*)d_out;
  float* nextA = out;
  float* nextB = out + (long)Bn * 1024;
  float* dep = out + (long)2 * Bn * 1024;
  float* fo = dep + Bn;
  float* jo = fo + Bn;

  char* ws = (char*)d_ws;
  int* cnt = (int*)ws;
  int* list0 = (int*)(ws + 1024);
  int* list1 = (int*)(ws + 1024 + 16384);
  int* list2 = (int*)(ws + 1024 + 2 * 16384);
  int* list2i = (int*)(ws + 1024 + 3 * 16384);
  float* nb11ws = (float*)(ws + 1 * MB_);
  float* na00ws = (float*)(ws + 9 * MB_);
  float* na10ws = (float*)(ws + 17 * MB_);
  unsigned short* Wa10p = (unsigned short*)(ws + 25 * MB_);
  unsigned short* Wb10p = (unsigned short*)(ws + 27 * MB_);
  unsigned short* Wb11p = (unsigned short*)(ws + 29 * MB_);
  unsigned short* Wa00p = (unsigned short*)(ws + 31 * MB_);
  unsigned short* Wb00p = (unsigned short*)(ws + 34 * MB_);

  // Zero counters before kprep (classify atomicAdds; block order is undefined,
  // so zeroing must precede the kernel — async memset is graph-capture-safe).
  hipMemsetAsync(cnt, 0, 64, stream);

  CvtArgs ca{};
  long gb = 0;
  auto seg = [&](int i, const float* s, unsigned short* d, int stride, int gprow, int rows) {
    ca.s[i].src = s; ca.s[i].dst = d; ca.s[i].srcStride = stride;
    ca.s[i].gprow = gprow; ca.s[i].gbase = gb;
    gb += (long)gprow * rows;
  };
  seg(0, Wa10, Wa10p, 1024, 128, 512);
  seg(1, Wb10, Wb10p, 1024, 128, 512);
  seg(2, Wb11, Wb11p, 1024, 128, 512);
  seg(3, Wa00, Wa00p, 1536, 192, 512);
  seg(4, Wb00, Wb00p, 1536, 192, 512);
  ca.total = gb;

  int clsBlocks = (Bn + 255) / 256;
  kprep<<<1024 + clsBlocks, 256, 0, stream>>>(nextA, nextB, ca, pdep, dep, fo, jo,
                                              cnt, list0, list1, Bn);

  GArgs Ga;
  Ga.X = X; Ga.pa = pa; Ga.pb = pb;
  Ga.nb11ws = nb11ws; Ga.na00ws = na00ws; Ga.na10ws = na10ws;
  Ga.Wa10p = Wa10p; Ga.Wb10p = Wb10p; Ga.Wb11p = Wb11p;
  Ga.Wa00p = Wa00p; Ga.Wb00p = Wb00p;
  Ga.nextA = nextA; Ga.nextB = nextB;
  Ga.cnt = cnt; Ga.list0 = list0; Ga.list1 = list1; Ga.list2 = list2; Ga.list2i = list2i;

  int nmb = (Bn + 63) / 64;
  int nm8 = ((nmb + 7) / 8) * 8;
  int bpm = nm8 * 8;

  gemm_mfma<<<3 * bpm, 256, 0, stream>>>(Ga, 0, bpm);  // G1: A10+B11+A00
  kselect<<<(Bn + 3) / 4, 256, 0, stream>>>(pa, pb, Watt, nb11ws, na00ws, nextA, nextB,
                                            dep, fo, jo, cnt, list1, list2, list2i);
  gemm_mfma<<<2 * bpm, 256, 0, stream>>>(Ga, 3, bpm);  // B10, K-split 2
  gemm_mfma<<<3 * bpm, 256, 0, stream>>>(Ga, 4, bpm);  // B00, K-split 3
}